// Round 1
// baseline (303.479 us; speedup 1.0000x reference)
//
#include <hip/hip_runtime.h>
#include <hip/hip_bf16.h>
#include <hip/hip_fp16.h>

// ScannedRNN (GRU with resets), T=512 B=256 H=INP=256, MI355X gfx950.
//
// Decomposition:
//  Kernel A (gi_proj): gi[t,b,g] = X @ w_ih^T + b_ih (+ b_hh folded for r,z gates),
//     stored f16 in d_ws. Register/LDS-resident bf16 w_ih fragments, 16-row chunks.
//  Kernel B (gru_scan): 16 time-chunks x 16 batch-tiles = 256 WGs (1/CU).
//     Each WG holds bf16 w_hh fragments resident (r,z in VGPRs, n in LDS),
//     scans its 32 steps + exact reset-based lookback. h state fp32 in regs.
//
// MFMA 16x16x32 bf16 layouts used (per cdna_hip_programming.md §3):
//   A: lane l holds A[l&15][ (l>>4)*8 + i ], i=0..7   (M=16 rows, K=32)
//   B: lane l holds B[ (l>>4)*8 + i ][ l&15 ]          (K=32, N=16 cols)
//   D: lane l reg j -> D[ (l>>4)*4 + j ][ l&15 ]       (verified m89/m91)

#define T_LEN 512
#define BATCH 256
#define HID   256
#define G3    768

typedef __attribute__((ext_vector_type(8))) short s16x8;   // 8 bf16 (4 VGPR)
typedef __attribute__((ext_vector_type(4))) float fx4;     // 4 f32 acc

#define MFMA16 __builtin_amdgcn_mfma_f32_16x16x32_bf16

__device__ __forceinline__ unsigned short f2bf(float f) {
  union { float f; unsigned u; } v; v.f = f;
  unsigned r = v.u + 0x7fffu + ((v.u >> 16) & 1u);   // RNE
  return (unsigned short)(r >> 16);
}

__device__ __forceinline__ s16x8 pack8(float4 a, float4 b) {
  s16x8 f;
  f[0] = (short)f2bf(a.x); f[1] = (short)f2bf(a.y);
  f[2] = (short)f2bf(a.z); f[3] = (short)f2bf(a.w);
  f[4] = (short)f2bf(b.x); f[5] = (short)f2bf(b.y);
  f[6] = (short)f2bf(b.z); f[7] = (short)f2bf(b.w);
  return f;
}

// Load 768x256 f32 weight matrix into bf16 MFMA B-fragments:
//   n-tile assignment: wave w owns gate columns {16w, 256+16w, 512+16w}
//   n=0,1 (r,z gates) -> VGPRs (wr[2][8]); n=2 (n gate) -> LDS (128 KiB).
__device__ __forceinline__ void load_weights(const float* __restrict__ W,
                                             s16x8 (&wr)[2][8], char* Wlds,
                                             int tid, int wid, int col, int kgrp) {
#pragma unroll
  for (int n = 0; n < 2; ++n) {
    int g = n * 256 + wid * 16 + col;
#pragma unroll
    for (int s8 = 0; s8 < 8; ++s8) {
      int k = s8 * 32 + kgrp * 8;
      const float4* p = (const float4*)(W + g * 256 + k);
      wr[n][s8] = pack8(p[0], p[1]);
    }
  }
#pragma unroll
  for (int q = 0; q < 8; ++q) {
    int li = tid + q * 1024;            // 8192 fragment lines of 16B
    int wv = li >> 9, s8 = (li >> 6) & 7, l = li & 63;
    int g = 512 + wv * 16 + (l & 15);
    int k = s8 * 32 + (l >> 4) * 8;
    const float4* p = (const float4*)(W + g * 256 + k);
    *(s16x8*)(Wlds + li * 16) = pack8(p[0], p[1]);
  }
}

// ---------------- Kernel A: input projection -> gi (f16) ----------------
__global__ __launch_bounds__(1024) void gi_proj_kernel(
    const float* __restrict__ X, const float* __restrict__ w_ih,
    const float* __restrict__ b_ih, const float* __restrict__ b_hh,
    __half* __restrict__ gi) {
  __shared__ __align__(16) char Wlds[131072];
  __shared__ __align__(16) char Ald[8192];   // 16x256 bf16, XOR-swizzled

  const int tid = threadIdx.x;
  const int wid = tid >> 6, lane = tid & 63;
  const int col = lane & 15, kgrp = lane >> 4;

  s16x8 wr[2][8];
  load_weights(w_ih, wr, Wlds, tid, wid, col, kgrp);

  float bias0, bias1, bias2;
  {
    int gb = wid * 16 + col;
    bias0 = b_ih[gb]       + b_hh[gb];        // fold b_hh for r
    bias1 = b_ih[256 + gb] + b_hh[256 + gb];  // fold b_hh for z
    bias2 = b_ih[512 + gb];                   // n-gate: b_hh applied in scan (r * (.))
  }

  const int e4 = tid * 4;
  const int srow = e4 >> 8, sk = e4 & 255;
  const unsigned sbyte = ((unsigned)(srow * 512 + sk * 2)) ^ ((unsigned)(srow & 7) << 4);

  float4 xcur = *(const float4*)(X + (size_t)(blockIdx.x * 16 + srow) * 256 + sk);

  for (int chunk = blockIdx.x; chunk < (T_LEN * BATCH) / 16; chunk += 256) {
    __syncthreads();   // prior iter's LDS reads done (also orders Wlds init)
    {
      unsigned lo = (unsigned)f2bf(xcur.x) | ((unsigned)f2bf(xcur.y) << 16);
      unsigned hi = (unsigned)f2bf(xcur.z) | ((unsigned)f2bf(xcur.w) << 16);
      uint2 v; v.x = lo; v.y = hi;
      *(uint2*)(Ald + sbyte) = v;
    }
    int nchunk = chunk + 256;
    if (nchunk < (T_LEN * BATCH) / 16)
      xcur = *(const float4*)(X + (size_t)(nchunk * 16 + srow) * 256 + sk);
    __syncthreads();

    fx4 acc0 = {0.f, 0.f, 0.f, 0.f}, acc1 = acc0, acc2 = acc0;
#pragma unroll
    for (int s8 = 0; s8 < 8; ++s8) {
      unsigned aoff = ((unsigned)(col * 512 + (s8 * 32 + kgrp * 8) * 2)) ^
                      ((unsigned)(col & 7) << 4);
      s16x8 af = *(const s16x8*)(Ald + aoff);
      s16x8 w2 = *(const s16x8*)(Wlds + ((wid * 8 + s8) * 64 + lane) * 16);
      acc0 = MFMA16(af, wr[0][s8], acc0, 0, 0, 0);
      acc1 = MFMA16(af, wr[1][s8], acc1, 0, 0, 0);
      acc2 = MFMA16(af, w2, acc2, 0, 0, 0);
    }

    size_t m0 = (size_t)chunk * 16;
#pragma unroll
    for (int j = 0; j < 4; ++j) {
      size_t m = m0 + kgrp * 4 + j;
      __half* gp = gi + m * G3 + wid * 16 + col;
      gp[0]   = __float2half(acc0[j] + bias0);
      gp[256] = __float2half(acc1[j] + bias1);
      gp[512] = __float2half(acc2[j] + bias2);
    }
  }
}

// ---------------- Kernel B: chunked GRU scan ----------------
__global__ __launch_bounds__(1024) void gru_scan_kernel(
    const float* __restrict__ carry, const __half* __restrict__ gi,
    const int* __restrict__ resets, const float* __restrict__ w_hh,
    const float* __restrict__ b_hh, float* __restrict__ out) {
  __shared__ __align__(16) char Wlds[131072];
  __shared__ __align__(16) char Ald[8192];   // h as bf16 A-tile, swizzled
  __shared__ int lastreset[16];

  const int tid = threadIdx.x;
  const int wid = tid >> 6, lane = tid & 63;
  const int col = lane & 15, kgrp = lane >> 4;
  const int c = blockIdx.x >> 4, bt = blockIdx.x & 15;
  const int b0 = bt * 16, t0 = c * 32, t1 = t0 + 32;
  const int hid = wid * 16 + col;

  s16x8 wr[2][8];
  load_weights(w_hh, wr, Wlds, tid, wid, col, kgrp);
  const float bhhn = b_hh[512 + hid];

  // ---- exact scan start: min over batch tile of (last reset < t0) ----
  int s, useCarry;
  if (c == 0) {
    s = 0; useCarry = 1;
  } else {
    if (tid < 16) lastreset[tid] = -1;
    for (int base = t0 - 64;; base -= 64) {
      __syncthreads();
      int tt = base + (tid >> 4);
      if (tt >= 0 && tt < t0) {
        if (resets[tt * BATCH + b0 + (tid & 15)] != 0)
          atomicMax(&lastreset[tid & 15], tt);
      }
      __syncthreads();
      int mn = t0, all = 1;
#pragma unroll
      for (int i = 0; i < 16; ++i) {
        int v = lastreset[i];
        all &= (v >= 0) ? 1 : 0;
        mn = min(mn, v < 0 ? t0 : v);
      }
      if (all) { s = mn; useCarry = 0; break; }
      if (base <= 0) { s = 0; useCarry = 1; break; }
    }
  }

  // ---- init state at t=s (reset[s] pre-applied) ----
  {
    int e4 = tid * 4, row = e4 >> 8, k = e4 & 255;
    int rst = resets[s * BATCH + b0 + row];
    float4 v = {0.f, 0.f, 0.f, 0.f};
    if (useCarry && !rst) v = *(const float4*)(carry + (size_t)(b0 + row) * HID + k);
    unsigned lo = (unsigned)f2bf(v.x) | ((unsigned)f2bf(v.y) << 16);
    unsigned hi = (unsigned)f2bf(v.z) | ((unsigned)f2bf(v.w) << 16);
    unsigned byteoff = ((unsigned)(row * 512 + k * 2)) ^ ((unsigned)(row & 7) << 4);
    uint2 u; u.x = lo; u.y = hi;
    *(uint2*)(Ald + byteoff) = u;
  }
  float hprev[4];
#pragma unroll
  for (int j = 0; j < 4; ++j) {
    int b = kgrp * 4 + j;
    int rst = resets[s * BATCH + b0 + b];
    float hv = 0.f;
    if (useCarry && !rst) hv = carry[(size_t)(b0 + b) * HID + hid];
    hprev[j] = hv;
  }
  __syncthreads();

  // ---- main scan ----
  for (int t = s; t < t1; ++t) {
    // gi prefetch (12 x u16, latency hidden under MFMA phase)
    __half gr[4], gz[4], gn[4];
#pragma unroll
    for (int j = 0; j < 4; ++j) {
      const __half* gp = gi + ((size_t)t * BATCH + b0 + kgrp * 4 + j) * G3 + hid;
      gr[j] = gp[0]; gz[j] = gp[256]; gn[j] = gp[512];
    }
    int4 rn = {0, 0, 0, 0};
    if (t + 1 < T_LEN) rn = *(const int4*)(resets + (t + 1) * BATCH + b0 + kgrp * 4);

    fx4 acc0 = {0.f, 0.f, 0.f, 0.f}, acc1 = acc0, acc2 = acc0;
#pragma unroll
    for (int s8 = 0; s8 < 8; ++s8) {
      unsigned aoff = ((unsigned)(col * 512 + (s8 * 32 + kgrp * 8) * 2)) ^
                      ((unsigned)(col & 7) << 4);
      s16x8 af = *(const s16x8*)(Ald + aoff);
      s16x8 w2 = *(const s16x8*)(Wlds + ((wid * 8 + s8) * 64 + lane) * 16);
      acc0 = MFMA16(af, wr[0][s8], acc0, 0, 0, 0);
      acc1 = MFMA16(af, wr[1][s8], acc1, 0, 0, 0);
      acc2 = MFMA16(af, w2, acc2, 0, 0, 0);
    }
    __syncthreads();   // all waves done reading Ald before it is rewritten

    const bool wr_out = (t >= t0);
    float* op = out + 65536 + ((size_t)t * BATCH + b0) * HID;
#pragma unroll
    for (int j = 0; j < 4; ++j) {
      int b = kgrp * 4 + j;
      float pr = __half2float(gr[j]) + acc0[j];            // b_ih+b_hh folded in gi
      float pz = __half2float(gz[j]) + acc1[j];
      float r = __builtin_amdgcn_rcpf(1.f + __expf(-pr));
      float z = __builtin_amdgcn_rcpf(1.f + __expf(-pz));
      float pn = __half2float(gn[j]) + r * (acc2[j] + bhhn);
      float n = 1.f - 2.f * __builtin_amdgcn_rcpf(1.f + __expf(2.f * pn));
      float hnew = (1.f - z) * n + z * hprev[j];
      if (wr_out) op[(size_t)b * HID + hid] = hnew;
      int rj = (j == 0) ? rn.x : (j == 1) ? rn.y : (j == 2) ? rn.z : rn.w;
      float hk = rj ? 0.f : hnew;                          // pre-apply reset[t+1]
      hprev[j] = hk;
      unsigned hoff = ((unsigned)(b * 512 + hid * 2)) ^ ((unsigned)(b & 7) << 4);
      *(unsigned short*)(Ald + hoff) = f2bf(hk);
    }
    __syncthreads();   // Ald(t+1) visible to all waves
  }

  if (c == 15) {       // h_final = h after t=511 (rn guarded -> untouched)
#pragma unroll
    for (int j = 0; j < 4; ++j)
      out[(size_t)(b0 + kgrp * 4 + j) * HID + hid] = hprev[j];
  }
}

extern "C" void kernel_launch(void* const* d_in, const int* in_sizes, int n_in,
                              void* d_out, int out_size, void* d_ws, size_t ws_size,
                              hipStream_t stream) {
  const float* carry = (const float*)d_in[0];
  const float* X     = (const float*)d_in[1];
  const int*   rsts  = (const int*)d_in[2];
  const float* w_ih  = (const float*)d_in[3];
  const float* w_hh  = (const float*)d_in[4];
  const float* b_ih  = (const float*)d_in[5];
  const float* b_hh  = (const float*)d_in[6];
  float* out = (float*)d_out;

  const size_t gi_bytes = (size_t)T_LEN * BATCH * G3 * sizeof(__half);  // 192 MiB
  if (ws_size < gi_bytes) return;  // ws too small -> clean fail (absmax ~= max|ref|)
  __half* gi = (__half*)d_ws;

  gi_proj_kernel<<<256, 1024, 0, stream>>>(X, w_ih, b_ih, b_hh, gi);
  gru_scan_kernel<<<256, 1024, 0, stream>>>(carry, gi, rsts, w_hh, b_hh, out);
}